// Round 1
// baseline (1764.496 us; speedup 1.0000x reference)
//
#include <hip/hip_runtime.h>
#include <math.h>

#define NT 4096        // tokens
#define DP 1024        // d_proj
#define DE 512         // d_embed
#define VCAB 50000
#define C0 10000
#define CUT1 30000
#define NHEAD 10002    // C0 + 2 cluster logits
#define TAILV 20000    // tokens per tail cluster

// ---------------- workspace layout ----------------
// H:      3 * NT * DE floats   (projected hidden for proj 0,1,2)
// S_head: NT floats            (sum of exp over head logits)
// S_tail: NT floats            (sum of exp over this token's tail logits)
// cnt:    4 ints               (tail token counts, padded)
// list:   2 * NT ints          (compacted token indices per tail)
#define H_FLOATS   (3u * NT * DE)
#define WS_SHEAD   (H_FLOATS)
#define WS_STAIL   (WS_SHEAD + NT)
#define WS_CNT     (WS_STAIL + NT)        // as int offset after cast
#define WS_LIST    (WS_CNT + 4)

// ---------------- cluster compaction ----------------
__global__ void cluster_kernel(const int* __restrict__ target,
                               int* __restrict__ cnt, int* __restrict__ list) {
    int t = blockIdx.x * blockDim.x + threadIdx.x;
    if (t >= NT) return;
    int tgt = target[t];
    int c = (tgt < C0) ? 0 : (tgt < CUT1 ? 1 : 2);
    if (c > 0) {
        int pos = atomicAdd(&cnt[c - 1], 1);
        list[(c - 1) * NT + pos] = t;
    }
}

// ---------------- projection GEMM: H[c] = hidden @ projs[c] ----------------
// A [NT,DP] row-major, B [DP,DE] row-major, C [NT,DE]
__global__ __launch_bounds__(256) void proj_kernel(const float* __restrict__ hidden,
                                                   const float* __restrict__ projs,
                                                   float* __restrict__ H) {
    const int c  = blockIdx.z;
    const int bm = blockIdx.y * 64;
    const int bn = blockIdx.x * 64;
    const float* A = hidden;
    const float* B = projs + (size_t)c * DP * DE;
    float* C = H + (size_t)c * NT * DE;

    __shared__ float As[16][64];   // [k][m]
    __shared__ float Bs[16][64];   // [k][n]

    const int tx = threadIdx.x, ty = threadIdx.y;
    const int tid = ty * 16 + tx;
    const int arow = tid >> 2, akg = (tid & 3) * 4;
    const int bk   = tid >> 4, bng = (tid & 15) * 4;

    float acc[4][4] = {};
    for (int kt = 0; kt < DP; kt += 16) {
        float4 av = *reinterpret_cast<const float4*>(&A[(size_t)(bm + arow) * DP + kt + akg]);
        float4 bv = *reinterpret_cast<const float4*>(&B[(size_t)(kt + bk) * DE + bn + bng]);
        As[akg + 0][arow] = av.x;
        As[akg + 1][arow] = av.y;
        As[akg + 2][arow] = av.z;
        As[akg + 3][arow] = av.w;
        *reinterpret_cast<float4*>(&Bs[bk][bng]) = bv;
        __syncthreads();
        #pragma unroll
        for (int k = 0; k < 16; ++k) {
            float4 a = *reinterpret_cast<const float4*>(&As[k][ty * 4]);
            float4 b = *reinterpret_cast<const float4*>(&Bs[k][tx * 4]);
            float ar[4] = {a.x, a.y, a.z, a.w}, br[4] = {b.x, b.y, b.z, b.w};
            #pragma unroll
            for (int i = 0; i < 4; ++i)
                #pragma unroll
                for (int j = 0; j < 4; ++j)
                    acc[i][j] += ar[i] * br[j];
        }
        __syncthreads();
    }
    #pragma unroll
    for (int i = 0; i < 4; ++i)
        #pragma unroll
        for (int j = 0; j < 4; ++j)
            C[(size_t)(bm + ty * 4 + i) * DE + bn + tx * 4 + j] = acc[i][j];
}

// ---------------- head pass: sum exp(H0 @ Whead^T + b) per token ----------------
__global__ __launch_bounds__(256) void head_kernel(const float* __restrict__ H,
                                                   const float* __restrict__ weight,
                                                   const float* __restrict__ bias,
                                                   const float* __restrict__ cw,
                                                   const float* __restrict__ cb,
                                                   float* __restrict__ S_head) {
    const int bm = blockIdx.y * 64;   // token block
    const int bn = blockIdx.x * 64;   // head-column block

    __shared__ float As[16][64];   // [k][m] from H0
    __shared__ float Bs[16][64];   // [k][j] from weight rows (gathered)
    __shared__ float Ps[64][16];   // row partial sums

    const int tx = threadIdx.x, ty = threadIdx.y;
    const int tid = ty * 16 + tx;
    const int arow = tid >> 2, akg = (tid & 3) * 4;

    float acc[4][4] = {};
    for (int kt = 0; kt < DE; kt += 16) {
        float4 av = *reinterpret_cast<const float4*>(&H[(size_t)(bm + arow) * DE + kt + akg]);
        int col = bn + arow;
        float4 wv = make_float4(0.f, 0.f, 0.f, 0.f);
        if (col < NHEAD) {
            const float* wr = (col < C0) ? &weight[(size_t)col * DE] : &cw[(size_t)(col - C0) * DE];
            wv = *reinterpret_cast<const float4*>(&wr[kt + akg]);
        }
        As[akg + 0][arow] = av.x;
        As[akg + 1][arow] = av.y;
        As[akg + 2][arow] = av.z;
        As[akg + 3][arow] = av.w;
        Bs[akg + 0][arow] = wv.x;
        Bs[akg + 1][arow] = wv.y;
        Bs[akg + 2][arow] = wv.z;
        Bs[akg + 3][arow] = wv.w;
        __syncthreads();
        #pragma unroll
        for (int k = 0; k < 16; ++k) {
            float4 a = *reinterpret_cast<const float4*>(&As[k][ty * 4]);
            float4 b = *reinterpret_cast<const float4*>(&Bs[k][tx * 4]);
            float ar[4] = {a.x, a.y, a.z, a.w}, br[4] = {b.x, b.y, b.z, b.w};
            #pragma unroll
            for (int i = 0; i < 4; ++i)
                #pragma unroll
                for (int j = 0; j < 4; ++j)
                    acc[i][j] += ar[i] * br[j];
        }
        __syncthreads();
    }
    // epilogue: exp + per-row partial sums
    #pragma unroll
    for (int i = 0; i < 4; ++i) {
        float s = 0.f;
        #pragma unroll
        for (int j = 0; j < 4; ++j) {
            int col = bn + tx * 4 + j;
            if (col < NHEAD) {
                float b = (col < C0) ? bias[col] : cb[col - C0];
                s += __expf(acc[i][j] + b);
            }
        }
        Ps[ty * 4 + i][tx] = s;
    }
    __syncthreads();
    if (tid < 64) {
        float s = 0.f;
        #pragma unroll
        for (int x = 0; x < 16; ++x) s += Ps[tid][x];
        atomicAdd(&S_head[bm + tid], s);
    }
}

// ---------------- tail pass: gathered tokens, one tail cluster each ----------------
__global__ __launch_bounds__(256) void tail_kernel(const float* __restrict__ H,
                                                   const float* __restrict__ weight,
                                                   const float* __restrict__ bias,
                                                   const int* __restrict__ cnt,
                                                   const int* __restrict__ list,
                                                   float* __restrict__ S_tail) {
    const int tail = blockIdx.z;          // 0 or 1
    const int n = cnt[tail];
    const int bm = blockIdx.y * 64;
    if (bm >= n) return;
    const int bn = blockIdx.x * 64;
    const int* lst = list + tail * NT;
    const float* A = H + (size_t)(1 + tail) * NT * DE;
    const int wbase = C0 + tail * TAILV;

    __shared__ float As[16][64];
    __shared__ float Bs[16][64];
    __shared__ float Ps[64][16];

    const int tx = threadIdx.x, ty = threadIdx.y;
    const int tid = ty * 16 + tx;
    const int arow = tid >> 2, akg = (tid & 3) * 4;

    int gm = bm + arow;
    int tok = (gm < n) ? lst[gm] : lst[0];   // dummy row for invalid (result discarded)

    float acc[4][4] = {};
    for (int kt = 0; kt < DE; kt += 16) {
        float4 av = *reinterpret_cast<const float4*>(&A[(size_t)tok * DE + kt + akg]);
        int col = bn + arow;
        float4 wv = make_float4(0.f, 0.f, 0.f, 0.f);
        if (col < TAILV) {
            wv = *reinterpret_cast<const float4*>(&weight[(size_t)(wbase + col) * DE + kt + akg]);
        }
        As[akg + 0][arow] = av.x;
        As[akg + 1][arow] = av.y;
        As[akg + 2][arow] = av.z;
        As[akg + 3][arow] = av.w;
        Bs[akg + 0][arow] = wv.x;
        Bs[akg + 1][arow] = wv.y;
        Bs[akg + 2][arow] = wv.z;
        Bs[akg + 3][arow] = wv.w;
        __syncthreads();
        #pragma unroll
        for (int k = 0; k < 16; ++k) {
            float4 a = *reinterpret_cast<const float4*>(&As[k][ty * 4]);
            float4 b = *reinterpret_cast<const float4*>(&Bs[k][tx * 4]);
            float ar[4] = {a.x, a.y, a.z, a.w}, br[4] = {b.x, b.y, b.z, b.w};
            #pragma unroll
            for (int i = 0; i < 4; ++i)
                #pragma unroll
                for (int j = 0; j < 4; ++j)
                    acc[i][j] += ar[i] * br[j];
        }
        __syncthreads();
    }
    #pragma unroll
    for (int i = 0; i < 4; ++i) {
        float s = 0.f;
        #pragma unroll
        for (int j = 0; j < 4; ++j) {
            int col = bn + tx * 4 + j;
            if (col < TAILV) s += __expf(acc[i][j] + bias[wbase + col]);
        }
        Ps[ty * 4 + i][tx] = s;
    }
    __syncthreads();
    if (tid < 64 && (bm + tid) < n) {
        float s = 0.f;
        #pragma unroll
        for (int x = 0; x < 16; ++x) s += Ps[tid][x];
        atomicAdd(&S_tail[lst[bm + tid]], s);
    }
}

// ---------------- finalize: target logits + assemble NLL ----------------
__global__ __launch_bounds__(64) void finalize_kernel(const float* __restrict__ H,
                                                      const int* __restrict__ target,
                                                      const float* __restrict__ weight,
                                                      const float* __restrict__ bias,
                                                      const float* __restrict__ cw,
                                                      const float* __restrict__ cb,
                                                      const float* __restrict__ S_head,
                                                      const float* __restrict__ S_tail,
                                                      float* __restrict__ out) {
    const int t = blockIdx.x;
    const int lane = threadIdx.x;
    const int tgt = target[t];
    const int c = (tgt < C0) ? 0 : (tgt < CUT1 ? 1 : 2);
    const float* h0 = &H[(size_t)t * DE];

    const float* w1;
    float b1;
    if (c == 0) { w1 = &weight[(size_t)tgt * DE]; b1 = bias[tgt]; }
    else        { w1 = &cw[(size_t)(c - 1) * DE]; b1 = cb[c - 1]; }

    float d1 = 0.f;
    for (int d = lane; d < DE; d += 64) d1 += h0[d] * w1[d];
    #pragma unroll
    for (int off = 32; off; off >>= 1) d1 += __shfl_down(d1, off);

    float d2 = 0.f;
    if (c > 0) {
        const float* hc = &H[((size_t)c * NT + t) * DE];
        const float* w2 = &weight[(size_t)tgt * DE];
        for (int d = lane; d < DE; d += 64) d2 += hc[d] * w2[d];
        #pragma unroll
        for (int off = 32; off; off >>= 1) d2 += __shfl_down(d2, off);
    }

    if (lane == 0) {
        float lsh = logf(S_head[t]);
        float res;
        if (c == 0) res = lsh - (d1 + b1);
        else        res = (lsh - (d1 + b1)) + (logf(S_tail[t]) - (d2 + bias[tgt]));
        out[t] = res;
    }
}

extern "C" void kernel_launch(void* const* d_in, const int* in_sizes, int n_in,
                              void* d_out, int out_size, void* d_ws, size_t ws_size,
                              hipStream_t stream) {
    const float* hidden = (const float*)d_in[0];
    const int*   target = (const int*)d_in[1];
    const float* weight = (const float*)d_in[2];
    const float* bias   = (const float*)d_in[3];
    const float* cw     = (const float*)d_in[4];
    const float* cb     = (const float*)d_in[5];
    const float* projs  = (const float*)d_in[6];
    float* out = (float*)d_out;

    float* H      = (float*)d_ws;
    float* S_head = H + H_FLOATS;
    float* S_tail = S_head + NT;
    int*   cnt    = (int*)(S_tail + NT);
    int*   list   = cnt + 4;

    // zero accumulators + counters (S_head, S_tail, cnt)
    hipMemsetAsync(S_head, 0, (2 * NT) * sizeof(float) + 4 * sizeof(int), stream);

    cluster_kernel<<<(NT + 255) / 256, 256, 0, stream>>>(target, cnt, list);
    proj_kernel<<<dim3(DE / 64, NT / 64, 3), dim3(16, 16), 0, stream>>>(hidden, projs, H);
    head_kernel<<<dim3((NHEAD + 63) / 64, NT / 64), dim3(16, 16), 0, stream>>>(
        H, weight, bias, cw, cb, S_head);
    tail_kernel<<<dim3((TAILV + 63) / 64, NT / 64, 2), dim3(16, 16), 0, stream>>>(
        H, weight, bias, cnt, list, S_tail);
    finalize_kernel<<<NT, 64, 0, stream>>>(H, target, weight, bias, cw, cb,
                                           S_head, S_tail, out);
}

// Round 2
// 571.831 us; speedup vs baseline: 3.0857x; 3.0857x over previous
//
#include <hip/hip_runtime.h>
#include <math.h>

#define NT 4096
#define DP 1024
#define DE 512
#define C0 10000
#define CUT1 30000
#define TAILV 20000
#define WROWS 50112   // 50000 weight rows + zero pad to cover last tail tile

typedef unsigned short ushort_t;
typedef short bf8 __attribute__((ext_vector_type(8)));
typedef float f4 __attribute__((ext_vector_type(4)));

__device__ __forceinline__ ushort_t f2b(float f) {
    union { float f; unsigned int u; } v; v.f = f;
    unsigned int r = v.u + 0x7FFFu + ((v.u >> 16) & 1u);
    return (ushort_t)(r >> 16);
}
__device__ __forceinline__ float b2f(ushort_t u) {
    union { unsigned int u; float f; } v; v.u = ((unsigned int)u) << 16; return v.f;
}

__device__ __forceinline__ void gld16(const void* g, void* l) {
    __builtin_amdgcn_global_load_lds(
        (const __attribute__((address_space(1))) unsigned int*)g,
        (__attribute__((address_space(3))) unsigned int*)l, 16, 0, 0);
}

// ---------------- cluster compaction ----------------
__global__ void cluster_kernel(const int* __restrict__ target,
                               int* __restrict__ cnt, int* __restrict__ list) {
    int t = blockIdx.x * blockDim.x + threadIdx.x;
    if (t >= NT) return;
    int tgt = target[t];
    int c = (tgt < C0) ? 0 : (tgt < CUT1 ? 1 : 2);
    if (c > 0) {
        int pos = atomicAdd(&cnt[c - 1], 1);
        list[(c - 1) * NT + pos] = t;
    }
}

// ---------------- fp32 -> bf16 cast (with zero pad region) ----------------
__global__ __launch_bounds__(256)
void cast_pad(const float* __restrict__ in, ushort_t* __restrict__ out,
              int total4, int valid) {
    int i = blockIdx.x * 256 + threadIdx.x;
    if (i >= total4) return;
    int base = i * 4;
    unsigned long long p = 0ull;
    if (base < valid) {
        float4 v = *reinterpret_cast<const float4*>(in + base);
        p = (unsigned long long)f2b(v.x)
          | ((unsigned long long)f2b(v.y) << 16)
          | ((unsigned long long)f2b(v.z) << 32)
          | ((unsigned long long)f2b(v.w) << 48);
    }
    *reinterpret_cast<unsigned long long*>(out + base) = p;
}

// ---------------- projs [3][1024][512] -> bf16 [3][512][1024] (transpose) ----
__global__ __launch_bounds__(256)
void transpose_cast(const float* __restrict__ projs, ushort_t* __restrict__ out) {
    const int cblk = blockIdx.z;
    const int n0 = blockIdx.x * 32;
    const int k0 = blockIdx.y * 32;
    __shared__ float tile[32][33];
    const int tx = threadIdx.x & 31, ty = threadIdx.x >> 5;
    const float* src = projs + (size_t)cblk * DP * DE;
    #pragma unroll
    for (int j = 0; j < 4; ++j)
        tile[ty + j * 8][tx] = src[(size_t)(k0 + ty + j * 8) * DE + n0 + tx];
    __syncthreads();
    ushort_t* dst = out + (size_t)cblk * DE * DP;
    #pragma unroll
    for (int j = 0; j < 4; ++j)
        dst[(size_t)(n0 + ty + j * 8) * DP + k0 + tx] = f2b(tile[tx][ty + j * 8]);
}

// ---------------- MFMA GEMM: C[m][n] = sum_k A[m][k] * B[n][k] ---------------
// MODE 0: proj   (A=hidden_b, B=projsT[c], out: Hb[c] bf16)
// MODE 1: head   (A=Hb[0], B=Wb, epilogue exp-sum -> S_head, mask col<validN)
// MODE 2: tail   (A=Hb[1+z] gathered via list, B=Wb+wbase, -> S_tail[token])
template<int MODE>
__global__ __launch_bounds__(256)
void gemm_bt(const ushort_t* __restrict__ Ab, const ushort_t* __restrict__ Bb,
             ushort_t* __restrict__ Cout, float* __restrict__ Sout,
             const float* __restrict__ bias,
             const int* __restrict__ cnt, const int* __restrict__ list,
             int K, int validN)
{
    const int tid = threadIdx.x;
    const int lane = tid & 63;
    const int wave = tid >> 6;
    const int wr = wave >> 1, wc = wave & 1;
    const int bm = blockIdx.y * 128;
    const int bn = blockIdx.x * 128;

    int n = 0;
    if (MODE == 0) {
        Bb += (size_t)blockIdx.z * DE * DP;
        Cout += (size_t)blockIdx.z * (size_t)NT * DE;
    }
    if (MODE == 2) {
        const int tail = blockIdx.z;
        n = cnt[tail];
        if (bm >= n) return;
        Ab += (size_t)(1 + tail) * NT * DE;
        Bb += (size_t)(C0 + tail * TAILV) * DE;
        bias += C0 + tail * TAILV;
        list += tail * NT;
    }

    __shared__ __align__(16) unsigned char lds[32768];
    unsigned char* As = lds;
    unsigned char* Bs = lds + 16384;

    // staging: 4 callsites x 4 waves x 64 lanes x 16B covers 128 rows x 128B.
    // LDS is linear [row][128B]; source k-slot is pre-swizzled: slot^=(row&7)
    const int kswz = (lane & 7) ^ ((lane >> 3) & 7);
    const int kbase = kswz * 8;          // element offset of the 16B chunk
    const int srow = wave * 8 + (lane >> 3);

    size_t arow[4], brow[4];
    #pragma unroll
    for (int s = 0; s < 4; ++s) {
        int lr = s * 32 + srow;
        int ga;
        if (MODE == 2) {
            int gr = bm + lr;
            ga = (gr < n) ? list[gr] : 0;
        } else ga = bm + lr;
        arow[s] = (size_t)ga * K;
        brow[s] = (size_t)(bn + lr) * K;
    }

    f4 acc[4][4];
    const f4 zero = {0.f, 0.f, 0.f, 0.f};
    #pragma unroll
    for (int i = 0; i < 4; ++i)
        #pragma unroll
        for (int j = 0; j < 4; ++j) acc[i][j] = zero;

    for (int kt = 0; kt < K; kt += 64) {
        if (kt) __syncthreads();
        #pragma unroll
        for (int s = 0; s < 4; ++s) {
            gld16(Ab + arow[s] + kt + kbase, As + s * 4096 + wave * 1024);
            gld16(Bb + brow[s] + kt + kbase, Bs + s * 4096 + wave * 1024);
        }
        __syncthreads();
        #pragma unroll
        for (int kh = 0; kh < 2; ++kh) {
            bf8 af[4], bv[4];
            #pragma unroll
            for (int i = 0; i < 4; ++i) {
                const int R = wr * 64 + i * 16 + (lane & 15);
                af[i] = *reinterpret_cast<const bf8*>(
                    As + R * 128 + (((kh * 4 + (lane >> 4)) ^ (R & 7)) << 4));
                const int Rb = wc * 64 + i * 16 + (lane & 15);
                bv[i] = *reinterpret_cast<const bf8*>(
                    Bs + Rb * 128 + (((kh * 4 + (lane >> 4)) ^ (Rb & 7)) << 4));
            }
            #pragma unroll
            for (int i = 0; i < 4; ++i)
                #pragma unroll
                for (int j = 0; j < 4; ++j)
                    acc[i][j] = __builtin_amdgcn_mfma_f32_16x16x32_bf16(
                        af[i], bv[j], acc[i][j], 0, 0, 0);
        }
    }

    if (MODE == 0) {
        #pragma unroll
        for (int i = 0; i < 4; ++i) {
            const int row = bm + wr * 64 + i * 16 + ((lane >> 4) << 2);
            #pragma unroll
            for (int j = 0; j < 4; ++j) {
                const int col = bn + wc * 64 + j * 16 + (lane & 15);
                #pragma unroll
                for (int r = 0; r < 4; ++r)
                    Cout[(size_t)(row + r) * DE + col] = f2b(acc[i][j][r]);
            }
        }
    } else {
        float rs[4][4];
        #pragma unroll
        for (int i = 0; i < 4; ++i)
            #pragma unroll
            for (int r = 0; r < 4; ++r) {
                float s = 0.f;
                #pragma unroll
                for (int j = 0; j < 4; ++j) {
                    const int col = bn + wc * 64 + j * 16 + (lane & 15);
                    if (col < validN) s += __expf(acc[i][j][r] + bias[col]);
                }
                rs[i][r] = s;
            }
        #pragma unroll
        for (int m = 1; m < 16; m <<= 1)
            #pragma unroll
            for (int i = 0; i < 4; ++i)
                #pragma unroll
                for (int r = 0; r < 4; ++r)
                    rs[i][r] += __shfl_xor(rs[i][r], m);
        if ((lane & 15) == 0) {
            const int rb = (lane >> 4) << 2;
            #pragma unroll
            for (int i = 0; i < 4; ++i)
                #pragma unroll
                for (int r = 0; r < 4; ++r) {
                    const int rloc = wr * 64 + i * 16 + rb + r;
                    if (MODE == 1) {
                        atomicAdd(&Sout[bm + rloc], rs[i][r]);
                    } else {
                        int gm = bm + rloc;
                        if (gm < n) atomicAdd(&Sout[list[gm]], rs[i][r]);
                    }
                }
        }
    }
}

// ---------------- finalize: cluster logits + target logit + NLL --------------
__global__ __launch_bounds__(64)
void finalize_kernel(const ushort_t* __restrict__ Hb, const int* __restrict__ target,
                     const float* __restrict__ weight, const float* __restrict__ bias,
                     const float* __restrict__ cw, const float* __restrict__ cb,
                     const float* __restrict__ S_head, const float* __restrict__ S_tail,
                     float* __restrict__ out)
{
    const int t = blockIdx.x, lane = threadIdx.x;
    const int tgt = target[t];
    const int c = (tgt < C0) ? 0 : (tgt < CUT1 ? 1 : 2);
    const int e = lane * 8;

    union { uint4 u; ushort_t s[8]; } h0;
    h0.u = *reinterpret_cast<const uint4*>(Hb + (size_t)t * DE + e);
    float hv[8];
    #pragma unroll
    for (int k = 0; k < 8; ++k) hv[k] = b2f(h0.s[k]);

    float c1 = 0.f, c2 = 0.f;
    #pragma unroll
    for (int k = 0; k < 8; ++k) {
        c1 += hv[k] * cw[e + k];
        c2 += hv[k] * cw[DE + e + k];
    }

    const ushort_t* hs = (c == 0) ? (Hb + (size_t)t * DE)
                                  : (Hb + ((size_t)c * NT + (size_t)t) * DE);
    union { uint4 u; ushort_t s[8]; } hc;
    hc.u = *reinterpret_cast<const uint4*>(hs + e);
    const float* wt = weight + (size_t)tgt * DE;
    float dt = 0.f;
    #pragma unroll
    for (int k = 0; k < 8; ++k) dt += b2f(hc.s[k]) * wt[e + k];

    #pragma unroll
    for (int m = 32; m; m >>= 1) {
        c1 += __shfl_xor(c1, m);
        c2 += __shfl_xor(c2, m);
        dt += __shfl_xor(dt, m);
    }
    if (lane == 0) {
        c1 += cb[0]; c2 += cb[1];
        const float S = S_head[t] + __expf(c1) + __expf(c2);
        const float lsh = logf(S);
        float res;
        if (c == 0) {
            res = lsh - (dt + bias[tgt]);
        } else {
            const float cl = (c == 1) ? c1 : c2;
            res = (lsh - cl) + (logf(S_tail[t]) - (dt + bias[tgt]));
        }
        out[t] = res;
    }
}

extern "C" void kernel_launch(void* const* d_in, const int* in_sizes, int n_in,
                              void* d_out, int out_size, void* d_ws, size_t ws_size,
                              hipStream_t stream) {
    const float* hidden = (const float*)d_in[0];
    const int*   target = (const int*)d_in[1];
    const float* weight = (const float*)d_in[2];
    const float* bias   = (const float*)d_in[3];
    const float* cw     = (const float*)d_in[4];
    const float* cb     = (const float*)d_in[5];
    const float* projs  = (const float*)d_in[6];
    float* out = (float*)d_out;

    char* w = (char*)d_ws;
    ushort_t* Hb      = (ushort_t*)w;  w += (size_t)3 * NT * DE * 2;
    ushort_t* hiddenb = (ushort_t*)w;  w += (size_t)NT * DP * 2;
    ushort_t* Wb      = (ushort_t*)w;  w += (size_t)WROWS * DE * 2;
    ushort_t* projsTb = (ushort_t*)w;  w += (size_t)3 * DE * DP * 2;
    float* S_head = (float*)w;         w += NT * 4;
    float* S_tail = (float*)w;         w += NT * 4;
    int* cnt      = (int*)w;           w += 32;
    int* list     = (int*)w;           w += 2 * NT * 4;

    hipMemsetAsync(S_head, 0, NT * 4 * 2 + 32, stream);
    cluster_kernel<<<NT / 256, 256, 0, stream>>>(target, cnt, list);
    cast_pad<<<(NT * DP / 4 + 255) / 256, 256, 0, stream>>>(
        hidden, hiddenb, NT * DP / 4, NT * DP);
    cast_pad<<<(WROWS * DE / 4 + 255) / 256, 256, 0, stream>>>(
        weight, Wb, WROWS * DE / 4, 50000 * DE);
    transpose_cast<<<dim3(DE / 32, DP / 32, 3), 256, 0, stream>>>(projs, projsTb);

    gemm_bt<0><<<dim3(4, 32, 3), 256, 0, stream>>>(
        hiddenb, projsTb, Hb, nullptr, nullptr, nullptr, nullptr, DP, DE);
    gemm_bt<1><<<dim3(79, 32, 1), 256, 0, stream>>>(
        Hb, Wb, nullptr, S_head, bias, nullptr, nullptr, DE, C0);
    gemm_bt<2><<<dim3(157, 32, 2), 256, 0, stream>>>(
        Hb, Wb, nullptr, S_tail, bias, cnt, list, DE, TAILV);
    finalize_kernel<<<NT, 64, 0, stream>>>(
        Hb, target, weight, bias, cw, cb, S_head, S_tail, out);
}

// Round 3
// 428.037 us; speedup vs baseline: 4.1223x; 1.3359x over previous
//
#include <hip/hip_runtime.h>
#include <math.h>

#define NT 4096
#define DP 1024
#define DE 512
#define C0 10000
#define CUT1 30000
#define TAILV 20000
#define WROWS 50112   // 50000 weight rows + zero pad to cover last tail tile

typedef unsigned short ushort_t;
typedef short bf8 __attribute__((ext_vector_type(8)));
typedef float f4 __attribute__((ext_vector_type(4)));

__device__ __forceinline__ ushort_t f2b(float f) {
    union { float f; unsigned int u; } v; v.f = f;
    unsigned int r = v.u + 0x7FFFu + ((v.u >> 16) & 1u);
    return (ushort_t)(r >> 16);
}
__device__ __forceinline__ float b2f(ushort_t u) {
    union { unsigned int u; float f; } v; v.u = ((unsigned int)u) << 16; return v.f;
}

__device__ __forceinline__ void gld16(const void* g, void* l) {
    __builtin_amdgcn_global_load_lds(
        (const __attribute__((address_space(1))) unsigned int*)g,
        (__attribute__((address_space(3))) unsigned int*)l, 16, 0, 0);
}

// bijective XCD-chunk swizzle (m204): original round-robin id -> logical id
// such that each XCD owns a contiguous logical chunk.
__device__ __forceinline__ int xcd_swz(int wgid, int nwg) {
    int q = nwg >> 3, r = nwg & 7;
    int xcd = wgid & 7, idx = wgid >> 3;
    int base = (xcd < r) ? xcd * (q + 1) : r * (q + 1) + (xcd - r) * q;
    return base + idx;
}

// ---------------- cluster compaction ----------------
__global__ void cluster_kernel(const int* __restrict__ target,
                               int* __restrict__ cnt, int* __restrict__ list) {
    int t = blockIdx.x * blockDim.x + threadIdx.x;
    if (t >= NT) return;
    int tgt = target[t];
    int c = (tgt < C0) ? 0 : (tgt < CUT1 ? 1 : 2);
    if (c > 0) {
        int pos = atomicAdd(&cnt[c - 1], 1);
        list[(c - 1) * NT + pos] = t;
    }
}

// ---------------- fp32 -> bf16 cast (with zero pad region) ----------------
__global__ __launch_bounds__(256)
void cast_pad(const float* __restrict__ in, ushort_t* __restrict__ out,
              int total4, int valid) {
    int i = blockIdx.x * 256 + threadIdx.x;
    if (i >= total4) return;
    int base = i * 4;
    unsigned long long p = 0ull;
    if (base < valid) {
        float4 v = *reinterpret_cast<const float4*>(in + base);
        p = (unsigned long long)f2b(v.x)
          | ((unsigned long long)f2b(v.y) << 16)
          | ((unsigned long long)f2b(v.z) << 32)
          | ((unsigned long long)f2b(v.w) << 48);
    }
    *reinterpret_cast<unsigned long long*>(out + base) = p;
}

// ---------------- projs [3][1024][512] -> bf16 [3][512][1024] (transpose) ----
__global__ __launch_bounds__(256)
void transpose_cast(const float* __restrict__ projs, ushort_t* __restrict__ out) {
    const int cblk = blockIdx.z;
    const int n0 = blockIdx.x * 32;
    const int k0 = blockIdx.y * 32;
    __shared__ float tile[32][33];
    const int tx = threadIdx.x & 31, ty = threadIdx.x >> 5;
    const float* src = projs + (size_t)cblk * DP * DE;
    #pragma unroll
    for (int j = 0; j < 4; ++j)
        tile[ty + j * 8][tx] = src[(size_t)(k0 + ty + j * 8) * DE + n0 + tx];
    __syncthreads();
    ushort_t* dst = out + (size_t)cblk * DE * DP;
    #pragma unroll
    for (int j = 0; j < 4; ++j)
        dst[(size_t)(n0 + ty + j * 8) * DP + k0 + tx] = f2b(tile[tx][ty + j * 8]);
}

// ---------------- MFMA GEMM: C[m][n] = sum_k A[m][k] * B[n][k] ---------------
// 128x128 tile, BK=64, 4 waves, double-buffered LDS + 2-phase prefetch.
// Flattened 1D grid: logical = xcd_swz(blockIdx.x); mblk = logical & 31
// (fastest -> consecutive logical blocks share the B-tile on one XCD).
// MODE 0: proj   (A=hidden_b, B=projsT[c], out: Hb[c] bf16)
// MODE 1: head   (A=Hb[0], B=Wb, epilogue exp-sum -> S_head, mask col<validN)
// MODE 2: tail   (A=Hb[1+z] gathered via list, B=Wb+wbase, -> S_tail[token])
template<int MODE>
__global__ __launch_bounds__(256)
void gemm_bt(const ushort_t* __restrict__ Ab, const ushort_t* __restrict__ Bb,
             ushort_t* __restrict__ Cout, float* __restrict__ Sout,
             const float* __restrict__ bias,
             const int* __restrict__ cnt, const int* __restrict__ list,
             int K, int validN)
{
    const int tid = threadIdx.x;
    const int lane = tid & 63;
    const int wave = tid >> 6;
    const int wr = wave >> 1, wc = wave & 1;

    const int logical = xcd_swz(blockIdx.x, gridDim.x);
    const int bm = (logical & 31) * 128;
    const int bn = (logical >> 5) * 128;

    int n = 0;
    if (MODE == 0) {
        Bb += (size_t)blockIdx.z * DE * DP;
        Cout += (size_t)blockIdx.z * (size_t)NT * DE;
    }
    if (MODE == 2) {
        const int tail = blockIdx.z;
        n = cnt[tail];
        if (bm >= n) return;
        Ab += (size_t)(1 + tail) * NT * DE;
        Bb += (size_t)(C0 + tail * TAILV) * DE;
        bias += C0 + tail * TAILV;
        list += tail * NT;
    }

    __shared__ __align__(16) unsigned char lds[65536];   // 2 x (16KB A + 16KB B)

    // staging: 4 callsites x 4 waves x 64 lanes x 16B covers 128 rows x 128B.
    // LDS is linear [row][128B]; source k-slot is pre-swizzled: slot^=(row&7)
    const int kswz = (lane & 7) ^ ((lane >> 3) & 7);
    const int kbase = kswz * 8;          // element offset of the 16B chunk
    const int srow = wave * 8 + (lane >> 3);

    size_t arow[4], brow[4];
    #pragma unroll
    for (int s = 0; s < 4; ++s) {
        int lr = s * 32 + srow;
        int ga;
        if (MODE == 2) {
            int gr = bm + lr;
            ga = (gr < n) ? list[gr] : 0;
        } else ga = bm + lr;
        arow[s] = (size_t)ga * K;
        brow[s] = (size_t)(bn + lr) * K;
    }

    f4 acc[4][4];
    const f4 zero = {0.f, 0.f, 0.f, 0.f};
    #pragma unroll
    for (int i = 0; i < 4; ++i)
        #pragma unroll
        for (int j = 0; j < 4; ++j) acc[i][j] = zero;

    auto stage = [&](int kt, unsigned char* base) {
        #pragma unroll
        for (int s = 0; s < 4; ++s) {
            gld16(Ab + arow[s] + kt + kbase, base + s * 4096 + wave * 1024);
            gld16(Bb + brow[s] + kt + kbase, base + 16384 + s * 4096 + wave * 1024);
        }
    };

    const int ntiles = K >> 6;
    stage(0, lds);
    __syncthreads();

    for (int t = 0; t < ntiles; ++t) {
        unsigned char* cur = lds + ((t & 1) << 15);
        if (t + 1 < ntiles)
            stage((t + 1) << 6, lds + (((t + 1) & 1) << 15));
        const unsigned char* As = cur;
        const unsigned char* Bs = cur + 16384;
        #pragma unroll
        for (int kh = 0; kh < 2; ++kh) {
            bf8 af[4], bv[4];
            #pragma unroll
            for (int i = 0; i < 4; ++i) {
                const int R = wr * 64 + i * 16 + (lane & 15);
                af[i] = *reinterpret_cast<const bf8*>(
                    As + R * 128 + (((kh * 4 + (lane >> 4)) ^ (R & 7)) << 4));
                const int Rb = wc * 64 + i * 16 + (lane & 15);
                bv[i] = *reinterpret_cast<const bf8*>(
                    Bs + Rb * 128 + (((kh * 4 + (lane >> 4)) ^ (Rb & 7)) << 4));
            }
            #pragma unroll
            for (int i = 0; i < 4; ++i)
                #pragma unroll
                for (int j = 0; j < 4; ++j)
                    acc[i][j] = __builtin_amdgcn_mfma_f32_16x16x32_bf16(
                        af[i], bv[j], acc[i][j], 0, 0, 0);
        }
        __syncthreads();   // drains stage(t+1) vmcnt + protects cur reuse
    }

    if (MODE == 0) {
        #pragma unroll
        for (int i = 0; i < 4; ++i) {
            const int row = bm + wr * 64 + i * 16 + ((lane >> 4) << 2);
            #pragma unroll
            for (int j = 0; j < 4; ++j) {
                const int col = bn + wc * 64 + j * 16 + (lane & 15);
                #pragma unroll
                for (int r = 0; r < 4; ++r)
                    Cout[(size_t)(row + r) * DE + col] = f2b(acc[i][j][r]);
            }
        }
    } else {
        float rs[4][4];
        #pragma unroll
        for (int i = 0; i < 4; ++i)
            #pragma unroll
            for (int r = 0; r < 4; ++r) {
                float s = 0.f;
                #pragma unroll
                for (int j = 0; j < 4; ++j) {
                    const int col = bn + wc * 64 + j * 16 + (lane & 15);
                    if (col < validN) s += __expf(acc[i][j][r] + bias[col]);
                }
                rs[i][r] = s;
            }
        #pragma unroll
        for (int m = 1; m < 16; m <<= 1)
            #pragma unroll
            for (int i = 0; i < 4; ++i)
                #pragma unroll
                for (int r = 0; r < 4; ++r)
                    rs[i][r] += __shfl_xor(rs[i][r], m);
        if ((lane & 15) == 0) {
            const int rb = (lane >> 4) << 2;
            #pragma unroll
            for (int i = 0; i < 4; ++i)
                #pragma unroll
                for (int r = 0; r < 4; ++r) {
                    const int rloc = wr * 64 + i * 16 + rb + r;
                    if (MODE == 1) {
                        atomicAdd(&Sout[bm + rloc], rs[i][r]);
                    } else {
                        int gm = bm + rloc;
                        if (gm < n) atomicAdd(&Sout[list[gm]], rs[i][r]);
                    }
                }
        }
    }
}

// ---------------- finalize: cluster logits + target logit + NLL --------------
__global__ __launch_bounds__(64)
void finalize_kernel(const ushort_t* __restrict__ Hb, const int* __restrict__ target,
                     const float* __restrict__ weight, const float* __restrict__ bias,
                     const float* __restrict__ cw, const float* __restrict__ cb,
                     const float* __restrict__ S_head, const float* __restrict__ S_tail,
                     float* __restrict__ out)
{
    const int t = blockIdx.x, lane = threadIdx.x;
    const int tgt = target[t];
    const int c = (tgt < C0) ? 0 : (tgt < CUT1 ? 1 : 2);
    const int e = lane * 8;

    union { uint4 u; ushort_t s[8]; } h0;
    h0.u = *reinterpret_cast<const uint4*>(Hb + (size_t)t * DE + e);
    float hv[8];
    #pragma unroll
    for (int k = 0; k < 8; ++k) hv[k] = b2f(h0.s[k]);

    float c1 = 0.f, c2 = 0.f;
    #pragma unroll
    for (int k = 0; k < 8; ++k) {
        c1 += hv[k] * cw[e + k];
        c2 += hv[k] * cw[DE + e + k];
    }

    const ushort_t* hs = (c == 0) ? (Hb + (size_t)t * DE)
                                  : (Hb + ((size_t)c * NT + (size_t)t) * DE);
    union { uint4 u; ushort_t s[8]; } hc;
    hc.u = *reinterpret_cast<const uint4*>(hs + e);
    const float* wt = weight + (size_t)tgt * DE;
    float dt = 0.f;
    #pragma unroll
    for (int k = 0; k < 8; ++k) dt += b2f(hc.s[k]) * wt[e + k];

    #pragma unroll
    for (int m = 32; m; m >>= 1) {
        c1 += __shfl_xor(c1, m);
        c2 += __shfl_xor(c2, m);
        dt += __shfl_xor(dt, m);
    }
    if (lane == 0) {
        c1 += cb[0]; c2 += cb[1];
        const float S = S_head[t] + __expf(c1) + __expf(c2);
        const float lsh = logf(S);
        float res;
        if (c == 0) {
            res = lsh - (dt + bias[tgt]);
        } else {
            const float cl = (c == 1) ? c1 : c2;
            res = (lsh - cl) + (logf(S_tail[t]) - (dt + bias[tgt]));
        }
        out[t] = res;
    }
}

extern "C" void kernel_launch(void* const* d_in, const int* in_sizes, int n_in,
                              void* d_out, int out_size, void* d_ws, size_t ws_size,
                              hipStream_t stream) {
    const float* hidden = (const float*)d_in[0];
    const int*   target = (const int*)d_in[1];
    const float* weight = (const float*)d_in[2];
    const float* bias   = (const float*)d_in[3];
    const float* cw     = (const float*)d_in[4];
    const float* cb     = (const float*)d_in[5];
    const float* projs  = (const float*)d_in[6];
    float* out = (float*)d_out;

    char* w = (char*)d_ws;
    ushort_t* Hb      = (ushort_t*)w;  w += (size_t)3 * NT * DE * 2;
    ushort_t* hiddenb = (ushort_t*)w;  w += (size_t)NT * DP * 2;
    ushort_t* Wb      = (ushort_t*)w;  w += (size_t)WROWS * DE * 2;
    ushort_t* projsTb = (ushort_t*)w;  w += (size_t)3 * DE * DP * 2;
    float* S_head = (float*)w;         w += NT * 4;
    float* S_tail = (float*)w;         w += NT * 4;
    int* cnt      = (int*)w;           w += 32;
    int* list     = (int*)w;           w += 2 * NT * 4;

    hipMemsetAsync(S_head, 0, NT * 4 * 2 + 32, stream);
    cluster_kernel<<<NT / 256, 256, 0, stream>>>(target, cnt, list);
    cast_pad<<<(NT * DP / 4 + 255) / 256, 256, 0, stream>>>(
        hidden, hiddenb, NT * DP / 4, NT * DP);
    cast_pad<<<(WROWS * DE / 4 + 255) / 256, 256, 0, stream>>>(
        weight, Wb, WROWS * DE / 4, 50000 * DE);
    transpose_cast<<<dim3(DE / 32, DP / 32, 3), 256, 0, stream>>>(projs, projsTb);

    // grids: x = MB(32) * NB, mblk fastest (B-tile reuse within XCD chunk)
    gemm_bt<0><<<dim3(32 * 4, 1, 3), 256, 0, stream>>>(
        hiddenb, projsTb, Hb, nullptr, nullptr, nullptr, nullptr, DP, DE);
    gemm_bt<1><<<dim3(32 * 79, 1, 1), 256, 0, stream>>>(
        Hb, Wb, nullptr, S_head, bias, nullptr, nullptr, DE, C0);
    gemm_bt<2><<<dim3(32 * 157, 1, 2), 256, 0, stream>>>(
        Hb, Wb, nullptr, S_tail, bias, cnt, list, DE, TAILV);
    finalize_kernel<<<NT, 64, 0, stream>>>(
        Hb, target, weight, bias, cw, cb, S_head, S_tail, out);
}

// Round 4
// 358.777 us; speedup vs baseline: 4.9181x; 1.1930x over previous
//
#include <hip/hip_runtime.h>
#include <math.h>

#define NT 4096
#define DP 1024
#define DE 512
#define C0 10000
#define CUT1 30000
#define TAILV 20000
#define WROWS 50112   // 50000 weight rows + zero pad to cover last tail tile

typedef unsigned short ushort_t;
typedef short bf8 __attribute__((ext_vector_type(8)));
typedef float f4 __attribute__((ext_vector_type(4)));

__device__ __forceinline__ ushort_t f2b(float f) {
    union { float f; unsigned int u; } v; v.f = f;
    unsigned int r = v.u + 0x7FFFu + ((v.u >> 16) & 1u);
    return (ushort_t)(r >> 16);
}
__device__ __forceinline__ float b2f(ushort_t u) {
    union { unsigned int u; float f; } v; v.u = ((unsigned int)u) << 16; return v.f;
}

__device__ __forceinline__ void gld16(const void* g, void* l) {
    __builtin_amdgcn_global_load_lds(
        (const __attribute__((address_space(1))) unsigned int*)g,
        (__attribute__((address_space(3))) unsigned int*)l, 16, 0, 0);
}

// bijective XCD-chunk swizzle (m204): each XCD owns a contiguous logical chunk
__device__ __forceinline__ int xcd_swz(int wgid, int nwg) {
    int q = nwg >> 3, r = nwg & 7;
    int xcd = wgid & 7, idx = wgid >> 3;
    int base = (xcd < r) ? xcd * (q + 1) : r * (q + 1) + (xcd - r) * q;
    return base + idx;
}

// ---------------- cluster compaction ----------------
__global__ void cluster_kernel(const int* __restrict__ target,
                               int* __restrict__ cnt, int* __restrict__ list) {
    int t = blockIdx.x * blockDim.x + threadIdx.x;
    if (t >= NT) return;
    int tgt = target[t];
    int c = (tgt < C0) ? 0 : (tgt < CUT1 ? 1 : 2);
    if (c > 0) {
        int pos = atomicAdd(&cnt[c - 1], 1);
        list[(c - 1) * NT + pos] = t;
    }
}

// ---------------- fp32 -> bf16 cast (with zero pad region) ----------------
__global__ __launch_bounds__(256)
void cast_pad(const float* __restrict__ in, ushort_t* __restrict__ out,
              int total4, int valid) {
    int i = blockIdx.x * 256 + threadIdx.x;
    if (i >= total4) return;
    int base = i * 4;
    unsigned long long p = 0ull;
    if (base < valid) {
        float4 v = *reinterpret_cast<const float4*>(in + base);
        p = (unsigned long long)f2b(v.x)
          | ((unsigned long long)f2b(v.y) << 16)
          | ((unsigned long long)f2b(v.z) << 32)
          | ((unsigned long long)f2b(v.w) << 48);
    }
    *reinterpret_cast<unsigned long long*>(out + base) = p;
}

// ---------------- projs [3][1024][512] -> bf16 [3][512][1024] (transpose) ----
__global__ __launch_bounds__(256)
void transpose_cast(const float* __restrict__ projs, ushort_t* __restrict__ out) {
    const int cblk = blockIdx.z;
    const int n0 = blockIdx.x * 32;
    const int k0 = blockIdx.y * 32;
    __shared__ float tile[32][33];
    const int tx = threadIdx.x & 31, ty = threadIdx.x >> 5;
    const float* src = projs + (size_t)cblk * DP * DE;
    #pragma unroll
    for (int j = 0; j < 4; ++j)
        tile[ty + j * 8][tx] = src[(size_t)(k0 + ty + j * 8) * DE + n0 + tx];
    __syncthreads();
    ushort_t* dst = out + (size_t)cblk * DE * DP;
    #pragma unroll
    for (int j = 0; j < 4; ++j)
        dst[(size_t)(n0 + ty + j * 8) * DP + k0 + tx] = f2b(tile[tx][ty + j * 8]);
}

// ---------------- MFMA GEMM: C[m][n] = sum_k A[m][k] * B[n][k] ---------------
// 128x128 tile, BK=64, 4 waves, SINGLE-buffered 32KB LDS (m97 structure):
// 4 blocks/CU -> cross-block overlap covers the stage drain (m114).
// Flattened 1D grid: logical = xcd_swz(blockIdx.x); mblk = logical & 31
// (fastest -> consecutive logical blocks share the B-tile on one XCD).
// MODE 0: proj   (A=hidden_b, B=projsT[c], out: Hb[c] bf16)
// MODE 1: head   (A=Hb[0], B=Wb, epilogue exp-sum -> S_head, mask col<validN)
// MODE 2: tail   (A=Hb[1+z] gathered via list, B=Wb+wbase, -> S_tail[token])
template<int MODE>
__global__ __launch_bounds__(256, 4)
void gemm_bt(const ushort_t* __restrict__ Ab, const ushort_t* __restrict__ Bb,
             ushort_t* __restrict__ Cout, float* __restrict__ Sout,
             const float* __restrict__ bias,
             const int* __restrict__ cnt, const int* __restrict__ list,
             int K, int validN)
{
    const int tid = threadIdx.x;
    const int lane = tid & 63;
    const int wave = tid >> 6;
    const int wr = wave >> 1, wc = wave & 1;

    const int logical = xcd_swz(blockIdx.x, gridDim.x);
    const int bm = (logical & 31) * 128;
    const int bn = (logical >> 5) * 128;

    int n = 0;
    if (MODE == 0) {
        Bb += (size_t)blockIdx.z * DE * DP;
        Cout += (size_t)blockIdx.z * (size_t)NT * DE;
    }
    if (MODE == 2) {
        const int tail = blockIdx.z;
        n = cnt[tail];
        if (bm >= n) return;
        Ab += (size_t)(1 + tail) * NT * DE;
        Bb += (size_t)(C0 + tail * TAILV) * DE;
        bias += C0 + tail * TAILV;
        list += tail * NT;
    }

    __shared__ __align__(16) unsigned char lds[32768];
    unsigned char* As = lds;
    unsigned char* Bs = lds + 16384;

    // staging: 4 callsites x 4 waves x 64 lanes x 16B covers 128 rows x 128B.
    // LDS is linear [row][128B]; source k-slot is pre-swizzled: slot^=(row&7)
    const int kswz = (lane & 7) ^ ((lane >> 3) & 7);
    const int kbase = kswz * 8;          // element offset of the 16B chunk
    const int srow = wave * 8 + (lane >> 3);

    size_t arow[4], brow[4];
    #pragma unroll
    for (int s = 0; s < 4; ++s) {
        int lr = s * 32 + srow;
        int ga;
        if (MODE == 2) {
            int gr = bm + lr;
            ga = (gr < n) ? list[gr] : 0;
        } else ga = bm + lr;
        arow[s] = (size_t)ga * K;
        brow[s] = (size_t)(bn + lr) * K;
    }

    f4 acc[4][4];
    const f4 zero = {0.f, 0.f, 0.f, 0.f};
    #pragma unroll
    for (int i = 0; i < 4; ++i)
        #pragma unroll
        for (int j = 0; j < 4; ++j) acc[i][j] = zero;

    for (int kt = 0; kt < K; kt += 64) {
        if (kt) __syncthreads();
        #pragma unroll
        for (int s = 0; s < 4; ++s) {
            gld16(Ab + arow[s] + kt + kbase, As + s * 4096 + wave * 1024);
            gld16(Bb + brow[s] + kt + kbase, Bs + s * 4096 + wave * 1024);
        }
        __syncthreads();
        #pragma unroll
        for (int kh = 0; kh < 2; ++kh) {
            bf8 af[4], bv[4];
            #pragma unroll
            for (int i = 0; i < 4; ++i) {
                const int R = wr * 64 + i * 16 + (lane & 15);
                af[i] = *reinterpret_cast<const bf8*>(
                    As + R * 128 + (((kh * 4 + (lane >> 4)) ^ (R & 7)) << 4));
                const int Rb = wc * 64 + i * 16 + (lane & 15);
                bv[i] = *reinterpret_cast<const bf8*>(
                    Bs + Rb * 128 + (((kh * 4 + (lane >> 4)) ^ (Rb & 7)) << 4));
            }
            #pragma unroll
            for (int i = 0; i < 4; ++i)
                #pragma unroll
                for (int j = 0; j < 4; ++j)
                    acc[i][j] = __builtin_amdgcn_mfma_f32_16x16x32_bf16(
                        af[i], bv[j], acc[i][j], 0, 0, 0);
        }
    }

    if (MODE == 0) {
        #pragma unroll
        for (int i = 0; i < 4; ++i) {
            const int row = bm + wr * 64 + i * 16 + ((lane >> 4) << 2);
            #pragma unroll
            for (int j = 0; j < 4; ++j) {
                const int col = bn + wc * 64 + j * 16 + (lane & 15);
                #pragma unroll
                for (int r = 0; r < 4; ++r)
                    Cout[(size_t)(row + r) * DE + col] = f2b(acc[i][j][r]);
            }
        }
    } else {
        float rs[4][4];
        #pragma unroll
        for (int i = 0; i < 4; ++i)
            #pragma unroll
            for (int r = 0; r < 4; ++r) {
                float s = 0.f;
                #pragma unroll
                for (int j = 0; j < 4; ++j) {
                    const int col = bn + wc * 64 + j * 16 + (lane & 15);
                    if (col < validN) s += __expf(acc[i][j][r] + bias[col]);
                }
                rs[i][r] = s;
            }
        #pragma unroll
        for (int m = 1; m < 16; m <<= 1)
            #pragma unroll
            for (int i = 0; i < 4; ++i)
                #pragma unroll
                for (int r = 0; r < 4; ++r)
                    rs[i][r] += __shfl_xor(rs[i][r], m);
        if ((lane & 15) == 0) {
            const int rb = (lane >> 4) << 2;
            #pragma unroll
            for (int i = 0; i < 4; ++i)
                #pragma unroll
                for (int r = 0; r < 4; ++r) {
                    const int rloc = wr * 64 + i * 16 + rb + r;
                    if (MODE == 1) {
                        atomicAdd(&Sout[bm + rloc], rs[i][r]);
                    } else {
                        int gm = bm + rloc;
                        if (gm < n) atomicAdd(&Sout[list[gm]], rs[i][r]);
                    }
                }
        }
    }
}

// ---------------- finalize: cluster logits + target logit + NLL --------------
__global__ __launch_bounds__(64)
void finalize_kernel(const ushort_t* __restrict__ Hb, const int* __restrict__ target,
                     const float* __restrict__ weight, const float* __restrict__ bias,
                     const float* __restrict__ cw, const float* __restrict__ cb,
                     const float* __restrict__ S_head, const float* __restrict__ S_tail,
                     float* __restrict__ out)
{
    const int t = blockIdx.x, lane = threadIdx.x;
    const int tgt = target[t];
    const int c = (tgt < C0) ? 0 : (tgt < CUT1 ? 1 : 2);
    const int e = lane * 8;

    union { uint4 u; ushort_t s[8]; } h0;
    h0.u = *reinterpret_cast<const uint4*>(Hb + (size_t)t * DE + e);
    float hv[8];
    #pragma unroll
    for (int k = 0; k < 8; ++k) hv[k] = b2f(h0.s[k]);

    float c1 = 0.f, c2 = 0.f;
    #pragma unroll
    for (int k = 0; k < 8; ++k) {
        c1 += hv[k] * cw[e + k];
        c2 += hv[k] * cw[DE + e + k];
    }

    const ushort_t* hs = (c == 0) ? (Hb + (size_t)t * DE)
                                  : (Hb + ((size_t)c * NT + (size_t)t) * DE);
    union { uint4 u; ushort_t s[8]; } hc;
    hc.u = *reinterpret_cast<const uint4*>(hs + e);
    const float* wt = weight + (size_t)tgt * DE;
    float dt = 0.f;
    #pragma unroll
    for (int k = 0; k < 8; ++k) dt += b2f(hc.s[k]) * wt[e + k];

    #pragma unroll
    for (int m = 32; m; m >>= 1) {
        c1 += __shfl_xor(c1, m);
        c2 += __shfl_xor(c2, m);
        dt += __shfl_xor(dt, m);
    }
    if (lane == 0) {
        c1 += cb[0]; c2 += cb[1];
        const float S = S_head[t] + __expf(c1) + __expf(c2);
        const float lsh = logf(S);
        float res;
        if (c == 0) {
            res = lsh - (dt + bias[tgt]);
        } else {
            const float cl = (c == 1) ? c1 : c2;
            res = (lsh - cl) + (logf(S_tail[t]) - (dt + bias[tgt]));
        }
        out[t] = res;
    }
}

extern "C" void kernel_launch(void* const* d_in, const int* in_sizes, int n_in,
                              void* d_out, int out_size, void* d_ws, size_t ws_size,
                              hipStream_t stream) {
    const float* hidden = (const float*)d_in[0];
    const int*   target = (const int*)d_in[1];
    const float* weight = (const float*)d_in[2];
    const float* bias   = (const float*)d_in[3];
    const float* cw     = (const float*)d_in[4];
    const float* cb     = (const float*)d_in[5];
    const float* projs  = (const float*)d_in[6];
    float* out = (float*)d_out;

    char* w = (char*)d_ws;
    ushort_t* Hb      = (ushort_t*)w;  w += (size_t)3 * NT * DE * 2;
    ushort_t* hiddenb = (ushort_t*)w;  w += (size_t)NT * DP * 2;
    ushort_t* Wb      = (ushort_t*)w;  w += (size_t)WROWS * DE * 2;
    ushort_t* projsTb = (ushort_t*)w;  w += (size_t)3 * DE * DP * 2;
    float* S_head = (float*)w;         w += NT * 4;
    float* S_tail = (float*)w;         w += NT * 4;
    int* cnt      = (int*)w;           w += 32;
    int* list     = (int*)w;           w += 2 * NT * 4;

    hipMemsetAsync(S_head, 0, NT * 4 * 2 + 32, stream);
    cluster_kernel<<<NT / 256, 256, 0, stream>>>(target, cnt, list);
    cast_pad<<<(NT * DP / 4 + 255) / 256, 256, 0, stream>>>(
        hidden, hiddenb, NT * DP / 4, NT * DP);
    cast_pad<<<(WROWS * DE / 4 + 255) / 256, 256, 0, stream>>>(
        weight, Wb, WROWS * DE / 4, 50000 * DE);
    transpose_cast<<<dim3(DE / 32, DP / 32, 3), 256, 0, stream>>>(projs, projsTb);

    // grids: x = MB(32) * NB, mblk fastest (B-tile reuse within XCD chunk)
    gemm_bt<0><<<dim3(32 * 4, 1, 3), 256, 0, stream>>>(
        hiddenb, projsTb, Hb, nullptr, nullptr, nullptr, nullptr, DP, DE);
    gemm_bt<1><<<dim3(32 * 79, 1, 1), 256, 0, stream>>>(
        Hb, Wb, nullptr, S_head, bias, nullptr, nullptr, DE, C0);
    gemm_bt<2><<<dim3(32 * 157, 1, 2), 256, 0, stream>>>(
        Hb, Wb, nullptr, S_tail, bias, cnt, list, DE, TAILV);
    finalize_kernel<<<NT, 64, 0, stream>>>(
        Hb, target, weight, bias, cw, cb, S_head, S_tail, out);
}

// Round 5
// 298.756 us; speedup vs baseline: 5.9062x; 1.2009x over previous
//
#include <hip/hip_runtime.h>
#include <math.h>

#define NT 4096
#define DP 1024
#define DE 512
#define C0 10000
#define CUT1 30000
#define TAILV 20000
#define WROWS 50112   // 50000 weight rows + zero pad to cover last tail tile
#define NBH 79        // head n-blocks (10112/128)
#define NBT 157       // tail n-blocks (ceil(20000/128))

typedef unsigned short ushort_t;
typedef short bf8 __attribute__((ext_vector_type(8)));
typedef float f4 __attribute__((ext_vector_type(4)));

__device__ __forceinline__ ushort_t f2b(float f) {
    union { float f; unsigned int u; } v; v.f = f;
    unsigned int r = v.u + 0x7FFFu + ((v.u >> 16) & 1u);
    return (ushort_t)(r >> 16);
}
__device__ __forceinline__ float b2f(ushort_t u) {
    union { unsigned int u; float f; } v; v.u = ((unsigned int)u) << 16; return v.f;
}

__device__ __forceinline__ void gld16(const void* g, void* l) {
    __builtin_amdgcn_global_load_lds(
        (const __attribute__((address_space(1))) unsigned int*)g,
        (__attribute__((address_space(3))) unsigned int*)l, 16, 0, 0);
}

// bijective XCD-chunk swizzle (m204): each XCD owns a contiguous logical chunk
__device__ __forceinline__ int xcd_swz(int wgid, int nwg) {
    int q = nwg >> 3, r = nwg & 7;
    int xcd = wgid & 7, idx = wgid >> 3;
    int base = (xcd < r) ? xcd * (q + 1) : r * (q + 1) + (xcd - r) * q;
    return base + idx;
}

// ---------------- cluster compaction ----------------
__global__ void cluster_kernel(const int* __restrict__ target,
                               int* __restrict__ cnt, int* __restrict__ list) {
    int t = blockIdx.x * blockDim.x + threadIdx.x;
    if (t >= NT) return;
    int tgt = target[t];
    int c = (tgt < C0) ? 0 : (tgt < CUT1 ? 1 : 2);
    if (c > 0) {
        int pos = atomicAdd(&cnt[c - 1], 1);
        list[(c - 1) * NT + pos] = t;
    }
}

// ---------------- fp32 -> bf16 cast (with zero pad region) ----------------
__global__ __launch_bounds__(256)
void cast_pad(const float* __restrict__ in, ushort_t* __restrict__ out,
              int total4, int valid) {
    int i = blockIdx.x * 256 + threadIdx.x;
    if (i >= total4) return;
    int base = i * 4;
    unsigned long long p = 0ull;
    if (base < valid) {
        float4 v = *reinterpret_cast<const float4*>(in + base);
        p = (unsigned long long)f2b(v.x)
          | ((unsigned long long)f2b(v.y) << 16)
          | ((unsigned long long)f2b(v.z) << 32)
          | ((unsigned long long)f2b(v.w) << 48);
    }
    *reinterpret_cast<unsigned long long*>(out + base) = p;
}

// ---------------- projs [3][1024][512] -> bf16 [3][512][1024] (transpose) ----
__global__ __launch_bounds__(256)
void transpose_cast(const float* __restrict__ projs, ushort_t* __restrict__ out) {
    const int cblk = blockIdx.z;
    const int n0 = blockIdx.x * 32;
    const int k0 = blockIdx.y * 32;
    __shared__ float tile[32][33];
    const int tx = threadIdx.x & 31, ty = threadIdx.x >> 5;
    const float* src = projs + (size_t)cblk * DP * DE;
    #pragma unroll
    for (int j = 0; j < 4; ++j)
        tile[ty + j * 8][tx] = src[(size_t)(k0 + ty + j * 8) * DE + n0 + tx];
    __syncthreads();
    ushort_t* dst = out + (size_t)cblk * DE * DP;
    #pragma unroll
    for (int j = 0; j < 4; ++j)
        dst[(size_t)(n0 + ty + j * 8) * DP + k0 + tx] = f2b(tile[tx][ty + j * 8]);
}

// ---------------- MFMA GEMM: C[m][n] = sum_k A[m][k] * B[n][k] ---------------
// 128x128 tile, BK=64, 4 waves, single-buffered 32KB LDS (m97 structure).
// Flattened 1D grid: logical = xcd_swz(blockIdx.x); mblk = logical & 31.
// MODE 0: proj   (A=hidden_b, B=projsT[c], out: Hb[c] bf16)
// MODE 1: head   (A=Hb[0], B=Wb, epilogue exp-sum -> Ppart[nb][row])
// MODE 2: tail   (A=Hb[1+z] gathered via list, B=Wb+wbase, -> Ppart)
// NO cross-block atomics: each block stores its 128 partial row-sums to a
// private [nb][row] slice; a tiny reduce kernel sums over nb afterwards.
template<int MODE>
__global__ __launch_bounds__(256, 4)
void gemm_bt(const ushort_t* __restrict__ Ab, const ushort_t* __restrict__ Bb,
             ushort_t* __restrict__ Cout, float* __restrict__ Sout,
             const float* __restrict__ bias,
             const int* __restrict__ cnt, const int* __restrict__ list,
             int K, int validN)
{
    const int tid = threadIdx.x;
    const int lane = tid & 63;
    const int wave = tid >> 6;
    const int wr = wave >> 1, wc = wave & 1;

    const int logical = xcd_swz(blockIdx.x, gridDim.x);
    const int bm = (logical & 31) * 128;
    const int bn = (logical >> 5) * 128;
    const int nb = logical >> 5;

    int n = 0;
    if (MODE == 0) {
        Bb += (size_t)blockIdx.z * DE * DP;
        Cout += (size_t)blockIdx.z * (size_t)NT * DE;
    }
    if (MODE == 2) {
        const int tail = blockIdx.z;
        n = cnt[tail];
        if (bm >= n) return;
        Ab += (size_t)(1 + tail) * NT * DE;
        Bb += (size_t)(C0 + tail * TAILV) * DE;
        bias += C0 + tail * TAILV;
        list += tail * NT;
        Sout += (size_t)tail * NBT * NT;
    }

    __shared__ __align__(16) unsigned char lds[32768];
    unsigned char* As = lds;
    unsigned char* Bs = lds + 16384;

    // staging: 4 callsites x 4 waves x 64 lanes x 16B covers 128 rows x 128B.
    // LDS is linear [row][128B]; source k-slot is pre-swizzled: slot^=(row&7)
    const int kswz = (lane & 7) ^ ((lane >> 3) & 7);
    const int kbase = kswz * 8;          // element offset of the 16B chunk
    const int srow = wave * 8 + (lane >> 3);

    size_t arow[4], brow[4];
    #pragma unroll
    for (int s = 0; s < 4; ++s) {
        int lr = s * 32 + srow;
        int ga;
        if (MODE == 2) {
            int gr = bm + lr;
            ga = (gr < n) ? list[gr] : 0;
        } else ga = bm + lr;
        arow[s] = (size_t)ga * K;
        brow[s] = (size_t)(bn + lr) * K;
    }

    f4 acc[4][4];
    const f4 zero = {0.f, 0.f, 0.f, 0.f};
    #pragma unroll
    for (int i = 0; i < 4; ++i)
        #pragma unroll
        for (int j = 0; j < 4; ++j) acc[i][j] = zero;

    for (int kt = 0; kt < K; kt += 64) {
        if (kt) __syncthreads();
        #pragma unroll
        for (int s = 0; s < 4; ++s) {
            gld16(Ab + arow[s] + kt + kbase, As + s * 4096 + wave * 1024);
            gld16(Bb + brow[s] + kt + kbase, Bs + s * 4096 + wave * 1024);
        }
        __syncthreads();
        #pragma unroll
        for (int kh = 0; kh < 2; ++kh) {
            bf8 af[4], bv[4];
            #pragma unroll
            for (int i = 0; i < 4; ++i) {
                const int R = wr * 64 + i * 16 + (lane & 15);
                af[i] = *reinterpret_cast<const bf8*>(
                    As + R * 128 + (((kh * 4 + (lane >> 4)) ^ (R & 7)) << 4));
                const int Rb = wc * 64 + i * 16 + (lane & 15);
                bv[i] = *reinterpret_cast<const bf8*>(
                    Bs + Rb * 128 + (((kh * 4 + (lane >> 4)) ^ (Rb & 7)) << 4));
            }
            #pragma unroll
            for (int i = 0; i < 4; ++i)
                #pragma unroll
                for (int j = 0; j < 4; ++j)
                    acc[i][j] = __builtin_amdgcn_mfma_f32_16x16x32_bf16(
                        af[i], bv[j], acc[i][j], 0, 0, 0);
        }
    }

    if (MODE == 0) {
        #pragma unroll
        for (int i = 0; i < 4; ++i) {
            const int row = bm + wr * 64 + i * 16 + ((lane >> 4) << 2);
            #pragma unroll
            for (int j = 0; j < 4; ++j) {
                const int col = bn + wc * 64 + j * 16 + (lane & 15);
                #pragma unroll
                for (int r = 0; r < 4; ++r)
                    Cout[(size_t)(row + r) * DE + col] = f2b(acc[i][j][r]);
            }
        }
    } else {
        float rs[4][4];
        #pragma unroll
        for (int i = 0; i < 4; ++i)
            #pragma unroll
            for (int r = 0; r < 4; ++r) {
                float s = 0.f;
                #pragma unroll
                for (int j = 0; j < 4; ++j) {
                    const int col = bn + wc * 64 + j * 16 + (lane & 15);
                    if (col < validN) s += __expf(acc[i][j][r] + bias[col]);
                }
                rs[i][r] = s;
            }
        #pragma unroll
        for (int m = 1; m < 16; m <<= 1)
            #pragma unroll
            for (int i = 0; i < 4; ++i)
                #pragma unroll
                for (int r = 0; r < 4; ++r)
                    rs[i][r] += __shfl_xor(rs[i][r], m);
        // cross-wave combine in LDS (reuse staging buffer), then plain store
        float* ps = (float*)lds;     // ps[wc][row], 2 x 128 floats
        __syncthreads();             // everyone done reading As/Bs
        if ((lane & 15) == 0) {
            const int rb = (lane >> 4) << 2;
            #pragma unroll
            for (int i = 0; i < 4; ++i)
                #pragma unroll
                for (int r = 0; r < 4; ++r)
                    ps[wc * 128 + wr * 64 + i * 16 + rb + r] = rs[i][r];
        }
        __syncthreads();
        if (tid < 128) {
            float v = ps[tid] + ps[128 + tid];
            Sout[(size_t)nb * NT + bm + tid] = v;   // partial; garbage rows unread
        }
    }
}

// ---------------- partial reduce: S = sum over n-blocks (no atomics) ---------
__global__ __launch_bounds__(256)
void reduce_kernel(const float* __restrict__ Ph, const float* __restrict__ Pt,
                   const int* __restrict__ cnt, const int* __restrict__ list,
                   float* __restrict__ S_head, float* __restrict__ S_tail) {
    const int z = blockIdx.y;
    const int t = blockIdx.x * 256 + threadIdx.x;
    if (z == 0) {
        if (t >= NT) return;
        float s = 0.f;
        for (int nb = 0; nb < NBH; ++nb) s += Ph[(size_t)nb * NT + t];
        S_head[t] = s;
    } else {
        const int tail = z - 1;
        if (t >= cnt[tail]) return;
        const float* P = Pt + (size_t)tail * NBT * NT;
        float s = 0.f;
        for (int nb = 0; nb < NBT; ++nb) s += P[(size_t)nb * NT + t];
        S_tail[list[tail * NT + t]] = s;
    }
}

// ---------------- finalize: cluster logits + target logit + NLL --------------
__global__ __launch_bounds__(64)
void finalize_kernel(const ushort_t* __restrict__ Hb, const int* __restrict__ target,
                     const float* __restrict__ weight, const float* __restrict__ bias,
                     const float* __restrict__ cw, const float* __restrict__ cb,
                     const float* __restrict__ S_head, const float* __restrict__ S_tail,
                     float* __restrict__ out)
{
    const int t = blockIdx.x, lane = threadIdx.x;
    const int tgt = target[t];
    const int c = (tgt < C0) ? 0 : (tgt < CUT1 ? 1 : 2);
    const int e = lane * 8;

    union { uint4 u; ushort_t s[8]; } h0;
    h0.u = *reinterpret_cast<const uint4*>(Hb + (size_t)t * DE + e);
    float hv[8];
    #pragma unroll
    for (int k = 0; k < 8; ++k) hv[k] = b2f(h0.s[k]);

    float c1 = 0.f, c2 = 0.f;
    #pragma unroll
    for (int k = 0; k < 8; ++k) {
        c1 += hv[k] * cw[e + k];
        c2 += hv[k] * cw[DE + e + k];
    }

    const ushort_t* hs = (c == 0) ? (Hb + (size_t)t * DE)
                                  : (Hb + ((size_t)c * NT + (size_t)t) * DE);
    union { uint4 u; ushort_t s[8]; } hc;
    hc.u = *reinterpret_cast<const uint4*>(hs + e);
    const float* wt = weight + (size_t)tgt * DE;
    float dt = 0.f;
    #pragma unroll
    for (int k = 0; k < 8; ++k) dt += b2f(hc.s[k]) * wt[e + k];

    #pragma unroll
    for (int m = 32; m; m >>= 1) {
        c1 += __shfl_xor(c1, m);
        c2 += __shfl_xor(c2, m);
        dt += __shfl_xor(dt, m);
    }
    if (lane == 0) {
        c1 += cb[0]; c2 += cb[1];
        const float S = S_head[t] + __expf(c1) + __expf(c2);
        const float lsh = logf(S);
        float res;
        if (c == 0) {
            res = lsh - (dt + bias[tgt]);
        } else {
            const float cl = (c == 1) ? c1 : c2;
            res = (lsh - cl) + (logf(S_tail[t]) - (dt + bias[tgt]));
        }
        out[t] = res;
    }
}

extern "C" void kernel_launch(void* const* d_in, const int* in_sizes, int n_in,
                              void* d_out, int out_size, void* d_ws, size_t ws_size,
                              hipStream_t stream) {
    const float* hidden = (const float*)d_in[0];
    const int*   target = (const int*)d_in[1];
    const float* weight = (const float*)d_in[2];
    const float* bias   = (const float*)d_in[3];
    const float* cw     = (const float*)d_in[4];
    const float* cb     = (const float*)d_in[5];
    const float* projs  = (const float*)d_in[6];
    float* out = (float*)d_out;

    char* w = (char*)d_ws;
    ushort_t* Hb      = (ushort_t*)w;  w += (size_t)3 * NT * DE * 2;
    ushort_t* hiddenb = (ushort_t*)w;  w += (size_t)NT * DP * 2;
    ushort_t* Wb      = (ushort_t*)w;  w += (size_t)WROWS * DE * 2;
    ushort_t* projsTb = (ushort_t*)w;  w += (size_t)3 * DE * DP * 2;
    float* S_head = (float*)w;         w += NT * 4;
    float* S_tail = (float*)w;         w += NT * 4;
    int* cnt      = (int*)w;           w += 32;
    int* list     = (int*)w;           w += 2 * NT * 4;
    float* Ph     = (float*)w;         w += (size_t)NBH * NT * 4;
    float* Pt     = (float*)w;         w += (size_t)2 * NBT * NT * 4;

    hipMemsetAsync(cnt, 0, 32, stream);
    cluster_kernel<<<NT / 256, 256, 0, stream>>>(target, cnt, list);
    cast_pad<<<(NT * DP / 4 + 255) / 256, 256, 0, stream>>>(
        hidden, hiddenb, NT * DP / 4, NT * DP);
    cast_pad<<<(WROWS * DE / 4 + 255) / 256, 256, 0, stream>>>(
        weight, Wb, WROWS * DE / 4, 50000 * DE);
    transpose_cast<<<dim3(DE / 32, DP / 32, 3), 256, 0, stream>>>(projs, projsTb);

    // grids: x = MB(32) * NB, mblk fastest (B-tile reuse within XCD chunk)
    gemm_bt<0><<<dim3(32 * 4, 1, 3), 256, 0, stream>>>(
        hiddenb, projsTb, Hb, nullptr, nullptr, nullptr, nullptr, DP, DE);
    gemm_bt<1><<<dim3(32 * NBH, 1, 1), 256, 0, stream>>>(
        Hb, Wb, nullptr, Ph, bias, nullptr, nullptr, DE, C0);
    gemm_bt<2><<<dim3(32 * NBT, 1, 2), 256, 0, stream>>>(
        Hb, Wb, nullptr, Pt, bias, cnt, list, DE, TAILV);
    reduce_kernel<<<dim3(NT / 256, 3), 256, 0, stream>>>(
        Ph, Pt, cnt, list, S_head, S_tail);
    finalize_kernel<<<NT, 64, 0, stream>>>(
        Hb, target, weight, bias, cw, cb, S_head, S_tail, out);
}